// Round 13
// baseline (86.936 us; speedup 1.0000x reference)
//
#include <hip/hip_runtime.h>
#include <hip/hip_bf16.h>

typedef __attribute__((ext_vector_type(4))) float f32x4;
typedef __attribute__((ext_vector_type(16))) float f32x16;
typedef __attribute__((ext_vector_type(8))) short bf16x8;

#define NH 8
#define HD 64
#define WSZ 128
#define DM 512

__device__ __forceinline__ unsigned int pk2bf(float lo, float hi) {
    union { __hip_bfloat162 h; unsigned int u; } r;
    r.h = __float22bfloat162_rn(make_float2(lo, hi));
    return r.u;
}

// One block = one (batch, window, head). 4 waves, each owns 32 q-columns of S^T.
// 32x32x16 MFMA; swapped QK^T -> S^T (lane-local softmax); P via
// cvt_pk + v_permlane32_swap (no LDS for P). LDS: K 16K + Vt 16K = 32K.
// KEY CHANGE vs r7: the 24 staging loads are pinned live via empty
// asm volatile "uses" so the register allocator MUST materialize all 24
// results at one point -> loads issue back-to-back, ONE latency window
// per tile instead of ~12-24 serialized exposures (r7's VGPR=68 proved
// IR-level sinking defeated the batch). launch_bounds(256,2) gives the
// ~150-VGPR budget this needs; occupancy 27->21% measured costless (r1-r7).
__global__ __launch_bounds__(256, 2) void wattn_kernel(
    const float* __restrict__ q1, const float* __restrict__ k1,
    const float* __restrict__ v1, float* __restrict__ o1, int nw1,
    const float* __restrict__ q2, const float* __restrict__ k2,
    const float* __restrict__ v2, float* __restrict__ o2, int nw2,
    int nblk1)
{
    // K tile bf16 [128][64], swizzled: idx = row*64 + (col ^ ((row&7)<<3))
    __shared__ __align__(16) unsigned short Kl[128 * 64];
    // V^T tile bf16 [64][128], swizzled: idx = d*128 + (k ^ (((d>>1)&7)<<3))
    __shared__ __align__(16) unsigned short Vt[64 * 128];

    const int t = threadIdx.x;
    const int lane = t & 63;
    const int wid = t >> 6;
    const int hi = lane >> 5;   // 0..1
    const int c = lane & 31;    // 0..31

    int bid = blockIdx.x;
    const float *q, *k, *v; float* o; int nw;
    if (bid < nblk1) { q = q1; k = k1; v = v1; o = o1; nw = nw1; }
    else { bid -= nblk1; q = q2; k = k2; v = v2; o = o2; nw = nw2; }

    const int h = bid & (NH - 1);
    const int w = (bid / NH) % nw;
    const int b = (bid / NH) / nw;

    const size_t row0 = ((size_t)b * nw + w) * WSZ;
    const float* Qp = q + row0 * DM + h * HD;
    const float* Kp = k + row0 * DM + h * HD;
    const float* Vp = v + row0 * DM + h * HD;
    float* Op = o + row0 * DM + h * HD;

    const int qbase = wid * 32;

    // ================= PHASE 1: issue ALL 24 loads =================
    f32x4 ka[4], kb[4], va[4], vb[4], qa[4], qb[4];
#pragma unroll
    for (int i = 0; i < 4; ++i) {               // K: coalesced rows
        const float* src = Kp + (size_t)(i * 32 + (t >> 3)) * DM + (t & 7) * 8;
        ka[i] = *reinterpret_cast<const f32x4*>(src);
        kb[i] = *reinterpret_cast<const f32x4*>(src + 4);
    }
#pragma unroll
    for (int i = 0; i < 4; ++i) {               // V: row-pairs
        int rp = i * 16 + (t >> 4);
        int dc = (t & 15) * 4;
        va[i] = *reinterpret_cast<const f32x4*>(Vp + (size_t)(2 * rp) * DM + dc);
        vb[i] = *reinterpret_cast<const f32x4*>(Vp + (size_t)(2 * rp + 1) * DM + dc);
    }
#pragma unroll
    for (int ks = 0; ks < 4; ++ks) {            // Q: B-fragment rows
        const float* src = Qp + (size_t)(qbase + c) * DM + ks * 16 + hi * 8;
        qa[ks] = *reinterpret_cast<const f32x4*>(src);
        qb[ks] = *reinterpret_cast<const f32x4*>(src + 4);
    }

    // Pin every load result live at this point: the allocator must hold all
    // 24 results simultaneously -> loads cannot be sunk to their uses ->
    // they issue back-to-back sharing one latency window. (rule-#17 idiom)
#pragma unroll
    for (int i = 0; i < 4; ++i) {
        asm volatile("" :: "v"(ka[i]), "v"(kb[i]), "v"(va[i]),
                          "v"(vb[i]), "v"(qa[i]), "v"(qb[i]));
    }
    __builtin_amdgcn_sched_barrier(0);

    // ================= PHASE 2: convert + stage =================
#pragma unroll
    for (int i = 0; i < 4; ++i) {
        int row = i * 32 + (t >> 3);
        int colf = (t & 7) * 8;
        int base = row * 64, sw = (row & 7) << 3;
        *reinterpret_cast<unsigned int*>(&Kl[base + (colf ^ sw)]) = pk2bf(ka[i][0], ka[i][1]);
        *reinterpret_cast<unsigned int*>(&Kl[base + ((colf + 2) ^ sw)]) = pk2bf(ka[i][2], ka[i][3]);
        *reinterpret_cast<unsigned int*>(&Kl[base + ((colf + 4) ^ sw)]) = pk2bf(kb[i][0], kb[i][1]);
        *reinterpret_cast<unsigned int*>(&Kl[base + ((colf + 6) ^ sw)]) = pk2bf(kb[i][2], kb[i][3]);
    }
#pragma unroll
    for (int i = 0; i < 4; ++i) {
        int rp = i * 16 + (t >> 4);
        int dc = (t & 15) * 4;
#pragma unroll
        for (int j = 0; j < 4; ++j) {
            int d = dc + j;
            *reinterpret_cast<unsigned int*>(
                &Vt[d * 128 + ((2 * rp) ^ (((d >> 1) & 7) << 3))]) = pk2bf(va[i][j], vb[i][j]);
        }
    }
    bf16x8 qf[4];
#pragma unroll
    for (int ks = 0; ks < 4; ++ks) {
        union { unsigned int u[4]; bf16x8 v; } r;
        r.u[0] = pk2bf(qa[ks][0], qa[ks][1]);
        r.u[1] = pk2bf(qa[ks][2], qa[ks][3]);
        r.u[2] = pk2bf(qb[ks][0], qb[ks][1]);
        r.u[3] = pk2bf(qb[ks][2], qb[ks][3]);
        qf[ks] = r.v;
    }

    __syncthreads();

    // ---- S^T = K Q^T : acc[mf], D: col=c (q), row k = mf*32+(reg&3)+8*(reg>>2)+4*hi
    f32x16 acc[4] = {};
#pragma unroll
    for (int ks = 0; ks < 4; ++ks) {
#pragma unroll
        for (int mf = 0; mf < 4; ++mf) {
            const bf16x8 kf = *reinterpret_cast<const bf16x8*>(
                &Kl[(mf * 32 + c) * 64 + ((ks * 16 + hi * 8) ^ ((c & 7) << 3))]);
            acc[mf] = __builtin_amdgcn_mfma_f32_32x32x16_bf16(kf, qf[ks], acc[mf], 0, 0, 0);
        }
    }

    // ---- softmax over k: lane-local, tree-reduced, one cross-half shfl ----
    const float CEXP = 0.125f * 1.4426950408889634f;
    float mxa = fmaxf(acc[0][0], acc[1][0]);
    float mxb = fmaxf(acc[2][0], acc[3][0]);
#pragma unroll
    for (int e = 1; e < 16; ++e) {
        mxa = fmaxf(mxa, fmaxf(acc[0][e], acc[1][e]));
        mxb = fmaxf(mxb, fmaxf(acc[2][e], acc[3][e]));
    }
    float mx = fmaxf(mxa, mxb);
    mx = fmaxf(mx, __shfl_xor(mx, 32));
    const float mxc = mx * CEXP;
    float s0 = 0.f, s1 = 0.f, s2 = 0.f, s3 = 0.f;
#pragma unroll
    for (int e = 0; e < 16; ++e) {
        float p0 = exp2f(acc[0][e] * CEXP - mxc);
        float p1 = exp2f(acc[1][e] * CEXP - mxc);
        float p2 = exp2f(acc[2][e] * CEXP - mxc);
        float p3 = exp2f(acc[3][e] * CEXP - mxc);
        acc[0][e] = p0; acc[1][e] = p1; acc[2][e] = p2; acc[3][e] = p3;
        s0 += p0; s1 += p1; s2 += p2; s3 += p3;
    }
    float sum = (s0 + s1) + (s2 + s3);
    sum += __shfl_xor(sum, 32);
    const float rinv = 1.0f / sum;

    // ---- O = P V : per 16-k block, pack P + permlane32_swap -> A-frag in regs ----
    f32x16 oacc[2] = {};
#pragma unroll
    for (int f = 0; f < 4; ++f) {
#pragma unroll
        for (int p = 0; p < 2; ++p) {
            const int kb2 = f * 2 + p;
            unsigned int U0 = pk2bf(acc[f][8 * p + 0], acc[f][8 * p + 1]);
            unsigned int U1 = pk2bf(acc[f][8 * p + 2], acc[f][8 * p + 3]);
            unsigned int U2 = pk2bf(acc[f][8 * p + 4], acc[f][8 * p + 5]);
            unsigned int U3 = pk2bf(acc[f][8 * p + 6], acc[f][8 * p + 7]);
            asm volatile("v_permlane32_swap_b32 %0, %1" : "+v"(U0), "+v"(U2));
            asm volatile("v_permlane32_swap_b32 %0, %1" : "+v"(U1), "+v"(U3));
            union { unsigned int u[4]; bf16x8 v; } A;
            A.u[0] = U0; A.u[1] = U1; A.u[2] = U2; A.u[3] = U3;
#pragma unroll
            for (int nf = 0; nf < 2; ++nf) {
                const int d = nf * 32 + c;
                const bf16x8 vf = *reinterpret_cast<const bf16x8*>(
                    &Vt[d * 128 + ((kb2 * 16 + hi * 8) ^ (((d >> 1) & 7) << 3))]);
                oacc[nf] = __builtin_amdgcn_mfma_f32_32x32x16_bf16(A.v, vf, oacc[nf], 0, 0, 0);
            }
        }
    }

    // ---- store O with deferred 1/rowsum broadcast from q-owner lanes ----
#pragma unroll
    for (int reg = 0; reg < 16; ++reg) {
        const int qr = (reg & 3) + 8 * (reg >> 2) + 4 * hi;
        const float rv = __shfl(rinv, qr);
#pragma unroll
        for (int nf = 0; nf < 2; ++nf) {
            Op[(size_t)(qbase + qr) * DM + nf * 32 + c] = oacc[nf][reg] * rv;
        }
    }
}

extern "C" void kernel_launch(void* const* d_in, const int* in_sizes, int n_in,
                              void* d_out, int out_size, void* d_ws, size_t ws_size,
                              hipStream_t stream) {
    const float* q1 = (const float*)d_in[0];
    const float* k1 = (const float*)d_in[1];
    const float* v1 = (const float*)d_in[2];
    const float* q2 = (const float*)d_in[3];
    const float* k2 = (const float*)d_in[4];
    const float* v2 = (const float*)d_in[5];

    const int B = 8;
    const int nw1 = in_sizes[0] / (B * DM * WSZ);   // 32
    const int nw2 = in_sizes[3] / (B * DM * WSZ);   // 16

    float* o1 = (float*)d_out;
    float* o2 = o1 + (size_t)in_sizes[0];

    const int nblk1 = B * nw1 * NH;                 // 2048
    const int nblk2 = B * nw2 * NH;                 // 1024

    wattn_kernel<<<dim3(nblk1 + nblk2), dim3(256), 0, stream>>>(
        q1, k1, v1, o1, nw1, q2, k2, v2, o2, nw2, nblk1);
}